// Round 1
// baseline (450.794 us; speedup 1.0000x reference)
//
#include <hip/hip_runtime.h>
#include <hip/hip_bf16.h>

#define HIDDEN 768
#define NB 8
#define BLK 96
#define S_LEN 8192
#define H_LEN 4096
#define M_LEN 4097
#define MP 4160           // spectrum word pitch (65*64); one (r,i) bf16 word per mode
#define BATCH 4
#define KBIG 192          // 2*BLK (interleaved r/i channels)
#define TMOD 64           // modes per MLP workgroup
#define MPITCH 66         // act LDS row pitch in bf16 elems (33 words, odd -> conflict-free)

#define TWO_PI 6.28318530717958647692f
#define INV_SQRT_N 0.011048543456039806f   // 1/sqrt(8192)
#define C_INV 0.022097086912079612f        // 2/sqrt(8192)
#define LAM 0.01f

// skewed LDS addressing: +1 float2 pad every 32 -> breaks stride-4/16/64 conflicts
#define LDSPAD(i) ((i) + ((i) >> 5))
#define LDS_SZ 4224       // 4095 + 127 + margin

typedef __attribute__((ext_vector_type(8))) short short8;
typedef __attribute__((ext_vector_type(4))) float float4v;

__device__ __forceinline__ int rev12(int k) {
    return (int)(__brev((unsigned)k) >> 20);
}
// base-4 digit reversal of a 12-bit index: bit-reverse then swap adjacent bit pairs
__device__ __forceinline__ int crev12(int k) {
    int r = rev12(k);
    return ((r & 0x555) << 1) | ((r >> 1) & 0x555);
}
__device__ __forceinline__ short f2bf(float f) {
    __hip_bfloat16 h = __float2bfloat16(f);
    return *reinterpret_cast<short*>(&h);
}
__device__ __forceinline__ float bf2f(unsigned short s) {
    __hip_bfloat16 h = *reinterpret_cast<__hip_bfloat16*>(&s);
    return __bfloat162float(h);
}

// ---------------------------------------------------------------------------
// P0: build bf16 big-weight matrices WT[n][out=192][kin=192] (kin interleaved
// r/i) for both layers, plus concatenated biases (fp32).
// ---------------------------------------------------------------------------
__global__ __launch_bounds__(256) void prep_weights(const float* __restrict__ w1,
                                                    const float* __restrict__ w2,
                                                    const float* __restrict__ b1,
                                                    const float* __restrict__ b2,
                                                    short* __restrict__ WT1,
                                                    short* __restrict__ WT2,
                                                    float* __restrict__ bb1,
                                                    float* __restrict__ bb2) {
    int idx = blockIdx.x * 256 + threadIdx.x;
    if (idx < NB * KBIG * KBIG) {
        int n = idx / (KBIG * KBIG);
        int r = idx % (KBIG * KBIG);
        int o = r / KBIG;
        int kin = r % KBIG;
        int d = kin >> 1;
        int im = kin & 1;
        {
            float w0 = w1[((size_t)(0 * NB + n) * BLK + d) * BLK + (o < BLK ? o : o - BLK)];
            float wi = w1[((size_t)(1 * NB + n) * BLK + d) * BLK + (o < BLK ? o : o - BLK)];
            float v = (o < BLK) ? (im ? -wi : w0) : (im ? w0 : wi);
            WT1[idx] = f2bf(v);
        }
        {
            float w0 = w2[((size_t)(0 * NB + n) * BLK + d) * BLK + (o < BLK ? o : o - BLK)];
            float wi = w2[((size_t)(1 * NB + n) * BLK + d) * BLK + (o < BLK ? o : o - BLK)];
            float v = (o < BLK) ? (im ? -wi : w0) : (im ? w0 : wi);
            WT2[idx] = f2bf(v);
        }
    }
    if (idx < NB * KBIG) {
        int n = idx / KBIG, o = idx % KBIG;
        bb1[idx] = (o < BLK) ? b1[(0 * NB + n) * BLK + o] : b1[(1 * NB + n) * BLK + o - BLK];
        bb2[idx] = (o < BLK) ? b2[(0 * NB + n) * BLK + o] : b2[(1 * NB + n) * BLK + o - BLK];
    }
}

// ---------------------------------------------------------------------------
// P1: twiddle tables (once per launch; sinf/cosf are MORE accurate than the
// per-butterfly __sincosf they replace).
//   tw4k[k] = exp(-2*pi*i*k/4096), k in [0,4096)
//   tw8k[m] = exp(-2*pi*i*m/8192), m in [0,4096]
// ---------------------------------------------------------------------------
__global__ __launch_bounds__(256) void init_twiddles(float2* __restrict__ tw4k,
                                                     float2* __restrict__ tw8k) {
    int i = blockIdx.x * 256 + threadIdx.x;
    if (i < 4096) {
        float ang = -TWO_PI * (float)i * (1.0f / 4096.0f);
        tw4k[i] = make_float2(cosf(ang), sinf(ang));
    }
    if (i <= 4096) {
        float ang = -TWO_PI * (float)i * (1.0f / 8192.0f);
        tw8k[i] = make_float2(cosf(ang), sinf(ang));
    }
}

// ---------------------------------------------------------------------------
// K0: x [B,S,C] f32  ->  xT [B*C, S] bf16   (32x32 LDS tiles, coalesced)
// ---------------------------------------------------------------------------
__global__ __launch_bounds__(256) void transpose_in(const float* __restrict__ x,
                                                    __hip_bfloat16* __restrict__ xT) {
    __shared__ float t[32][33];
    const int cb = blockIdx.x, sb = blockIdx.y, b = blockIdx.z;
    const int tx = threadIdx.x & 31, ty = threadIdx.x >> 5;
    const float* xp = x + ((size_t)b * S_LEN + sb * 32) * HIDDEN + cb * 32;
    for (int i = 0; i < 4; i++)
        t[ty + 8 * i][tx] = xp[(size_t)(ty + 8 * i) * HIDDEN + tx];
    __syncthreads();
    __hip_bfloat16* xq = xT + ((size_t)b * HIDDEN + cb * 32) * S_LEN + sb * 32;
    for (int i = 0; i < 4; i++)
        xq[(size_t)(ty + 8 * i) * S_LEN + tx] = __float2bfloat16(t[tx][ty + 8 * i]);
}

// ---------------------------------------------------------------------------
// Shared radix-4 DIT core: 6 stages over 4096 complex points in skewed LDS.
// Input must be base-4 digit-reversed. INV=false: exp(-i), INV=true: exp(+i)
// (unscaled). Ends with a barrier.
// ---------------------------------------------------------------------------
template<bool INV>
__device__ __forceinline__ void fft_stages(float2* zz, const float2* __restrict__ tw, int tid) {
    const float s3 = INV ? -1.f : 1.f;
    // stage 0: len=4, all twiddles = 1
    #pragma unroll
    for (int ii = 0; ii < 4; ii++) {
        int i = tid + (ii << 8);
        int base = i << 2;
        int i0 = LDSPAD(base), i1 = LDSPAD(base + 1), i2 = LDSPAD(base + 2), i3 = LDSPAD(base + 3);
        float2 x0 = zz[i0], x1 = zz[i1], x2 = zz[i2], x3 = zz[i3];
        float t0r = x0.x + x2.x, t0i = x0.y + x2.y;
        float u1r = x0.x - x2.x, u1i = x0.y - x2.y;
        float t2r = x1.x + x3.x, t2i = x1.y + x3.y;
        float t3r = x1.x - x3.x, t3i = x1.y - x3.y;
        zz[i0] = make_float2(t0r + t2r, t0i + t2i);
        zz[i2] = make_float2(t0r - t2r, t0i - t2i);
        zz[i1] = make_float2(u1r + s3 * t3i, u1i - s3 * t3r);
        zz[i3] = make_float2(u1r - s3 * t3i, u1i + s3 * t3r);
    }
    __syncthreads();
    // stages 1..5: len = 16,64,256,1024,4096
    #pragma unroll
    for (int s = 1; s < 6; s++) {
        const int q = 1 << (2 * s);
        const int shift = 10 - 2 * s;       // log2(4096/len)
        #pragma unroll
        for (int ii = 0; ii < 4; ii++) {
            int i = tid + (ii << 8);
            int j = i & (q - 1);
            int base = ((i - j) << 2) + j;
            int jw = j << shift;
            float2 w1 = tw[jw];
            float2 w2 = tw[jw * 2];
            float2 w3 = tw[jw * 3];
            float w1y = INV ? -w1.y : w1.y;
            float w2y = INV ? -w2.y : w2.y;
            float w3y = INV ? -w3.y : w3.y;
            int i0 = LDSPAD(base);
            int i1 = LDSPAD(base + q);
            int i2 = LDSPAD(base + 2 * q);
            int i3 = LDSPAD(base + 3 * q);
            float2 x0 = zz[i0], x1 = zz[i1], x2 = zz[i2], x3 = zz[i3];
            float a1r = x1.x * w1.x - x1.y * w1y, a1i = x1.x * w1y + x1.y * w1.x;
            float a2r = x2.x * w2.x - x2.y * w2y, a2i = x2.x * w2y + x2.y * w2.x;
            float a3r = x3.x * w3.x - x3.y * w3y, a3i = x3.x * w3y + x3.y * w3.x;
            float t0r = x0.x + a2r, t0i = x0.y + a2i;
            float u1r = x0.x - a2r, u1i = x0.y - a2i;
            float t2r = a1r + a3r, t2i = a1i + a3i;
            float t3r = a1r - a3r, t3i = a1i - a3i;
            zz[i0] = make_float2(t0r + t2r, t0i + t2i);
            zz[i2] = make_float2(t0r - t2r, t0i - t2i);
            zz[i1] = make_float2(u1r + s3 * t3i, u1i - s3 * t3r);
            zz[i3] = make_float2(u1r - s3 * t3i, u1i + s3 * t3r);
        }
        __syncthreads();
    }
}

// ---------------------------------------------------------------------------
// K1: forward rfft per (b,c) -> interleaved (r,i) bf16 words Xc[row][m]
// ---------------------------------------------------------------------------
__global__ __launch_bounds__(256, 4) void fft_fwd(const __hip_bfloat16* __restrict__ xT,
                                                  unsigned int* __restrict__ Xc,
                                                  const float2* __restrict__ tw4k,
                                                  const float2* __restrict__ tw8k) {
    __shared__ float2 zz[LDS_SZ];
    const int wg = blockIdx.x;           // b*HIDDEN + c
    const int tid = threadIdx.x;
    const __hip_bfloat162* xrow = (const __hip_bfloat162*)(xT + (size_t)wg * S_LEN);

    const int a = tid & 31, cb3 = tid >> 5;
    #pragma unroll
    for (int it = 0; it < 16; it++) {
        int k = (a << 7) | (it << 3) | cb3;        // bijective over [0,4096)
        __hip_bfloat162 v = xrow[k];               // z[k] = x[2k] + i x[2k+1]
        int c = crev12(k);
        zz[LDSPAD(c)] = make_float2(__bfloat162float(v.x), __bfloat162float(v.y));
    }
    __syncthreads();

    fft_stages<false>(zz, tw4k, tid);

    unsigned int* Xrow = Xc + (size_t)wg * MP;
    for (int m = tid; m <= H_LEN; m += 256) {
        int ia = m & (H_LEN - 1);
        int ib = (H_LEN - m) & (H_LEN - 1);
        float2 za = zz[LDSPAD(ia)];
        float2 zb = zz[LDSPAD(ib)];
        float er = 0.5f * (za.x + zb.x), ei = 0.5f * (za.y - zb.y);
        float dr = za.x - zb.x, di = za.y + zb.y;
        float or_ = 0.5f * di, oi = -0.5f * dr;
        float2 t = tw8k[m];                        // exp(-2*pi*i*m/8192)
        float wcs = t.x, wsn = t.y;
        float xrv = (er + wcs * or_ - wsn * oi) * INV_SQRT_N;
        float xiv = (ei + wcs * oi + wsn * or_) * INV_SQRT_N;
        unsigned wd = (unsigned short)f2bf(xrv) | ((unsigned)(unsigned short)f2bf(xiv) << 16);
        Xrow[m] = wd;
    }
}

// ---------------------------------------------------------------------------
// K2: MFMA block-diagonal complex MLP, in place over Xc.
// ---------------------------------------------------------------------------
__global__ __launch_bounds__(256) void mlp_mfma(const short* __restrict__ WT1,
                                                const short* __restrict__ WT2,
                                                const float* __restrict__ bb1,
                                                const float* __restrict__ bb2,
                                                unsigned int* __restrict__ Xc) {
    __shared__ short actA[KBIG * MPITCH];  // input, later final output
    __shared__ short actB[KBIG * MPITCH];  // layer-1 output
    const int tid = threadIdx.x;
    const int chunk = blockIdx.x;          // 0..64
    const int n = blockIdx.y;
    const int b = blockIdx.z;
    const int m0 = chunk * TMOD;
    unsigned int* __restrict__ Xrow0 =
        Xc + ((size_t)b * HIDDEN + (size_t)n * BLK) * MP + m0;

    // ---- stage: 96 channel rows x 64 modes, de-interleave to rows 2d / 2d+1
    {
        const int mw = tid & 31;           // word-pair: modes 2mw, 2mw+1
        const int dr = tid >> 5;           // 0..7
        int* a32 = (int*)actA;
        for (int pass = 0; pass < 12; pass++) {
            int d = dr + pass * 8;
            const uint2* src = (const uint2*)(Xrow0 + (size_t)d * MP);
            uint2 v = src[mw];
            unsigned rw = (v.x & 0xFFFFu) | (v.y << 16);
            unsigned iw = (v.x >> 16) | (v.y & 0xFFFF0000u);
            a32[(2 * d) * 33 + mw] = (int)rw;
            a32[(2 * d + 1) * 33 + mw] = (int)iw;
        }
    }
    __syncthreads();

    const int w = tid >> 6;
    const int l15 = tid & 15;
    const int q = (tid >> 4) & 3;
    const int outw = w * 48;

    // ---- layer 1 ----
    short8 wf[3][6];
    for (int nl = 0; nl < 3; nl++)
        for (int ks = 0; ks < 6; ks++)
            wf[nl][ks] = *(const short8*)(WT1 + ((size_t)n * KBIG + outw + nl * 16 + l15) * KBIG + ks * 32 + q * 8);

    for (int mt = 0; mt < 4; mt++) {
        float4v acc[3];
        for (int nl = 0; nl < 3; nl++)
            acc[nl] = *(const float4v*)(bb1 + n * KBIG + outw + nl * 16 + q * 4);
        for (int ks = 0; ks < 6; ks++) {
            short8 bf;
            const short* base = actA + (ks * 32 + q * 8) * MPITCH + mt * 16 + l15;
            #pragma unroll
            for (int j = 0; j < 8; j++) bf[j] = base[j * MPITCH];
            acc[0] = __builtin_amdgcn_mfma_f32_16x16x32_bf16(wf[0][ks], bf, acc[0], 0, 0, 0);
            acc[1] = __builtin_amdgcn_mfma_f32_16x16x32_bf16(wf[1][ks], bf, acc[1], 0, 0, 0);
            acc[2] = __builtin_amdgcn_mfma_f32_16x16x32_bf16(wf[2][ks], bf, acc[2], 0, 0, 0);
        }
        for (int nl = 0; nl < 3; nl++)
            #pragma unroll
            for (int reg = 0; reg < 4; reg++) {
                int out = outw + nl * 16 + q * 4 + reg;
                int row = (out < BLK) ? (out << 1) : (((out - BLK) << 1) | 1);
                actB[row * MPITCH + mt * 16 + l15] = f2bf(fmaxf(acc[nl][reg], 0.f));
            }
    }
    __syncthreads();

    // ---- layer 2 ----
    short8 wf2[3][6];
    for (int nl = 0; nl < 3; nl++)
        for (int ks = 0; ks < 6; ks++)
            wf2[nl][ks] = *(const short8*)(WT2 + ((size_t)n * KBIG + outw + nl * 16 + l15) * KBIG + ks * 32 + q * 8);

    for (int mt = 0; mt < 4; mt++) {
        float4v acc[3];
        for (int nl = 0; nl < 3; nl++)
            acc[nl] = *(const float4v*)(bb2 + n * KBIG + outw + nl * 16 + q * 4);
        for (int ks = 0; ks < 6; ks++) {
            short8 bf;
            const short* base = actB + (ks * 32 + q * 8) * MPITCH + mt * 16 + l15;
            #pragma unroll
            for (int j = 0; j < 8; j++) bf[j] = base[j * MPITCH];
            acc[0] = __builtin_amdgcn_mfma_f32_16x16x32_bf16(wf2[0][ks], bf, acc[0], 0, 0, 0);
            acc[1] = __builtin_amdgcn_mfma_f32_16x16x32_bf16(wf2[1][ks], bf, acc[1], 0, 0, 0);
            acc[2] = __builtin_amdgcn_mfma_f32_16x16x32_bf16(wf2[2][ks], bf, acc[2], 0, 0, 0);
        }
        for (int nl = 0; nl < 3; nl++)
            #pragma unroll
            for (int reg = 0; reg < 4; reg++) {
                int out = outw + nl * 16 + q * 4 + reg;
                float v = acc[nl][reg];
                v = copysignf(fmaxf(fabsf(v) - LAM, 0.f), v);
                actA[out * MPITCH + mt * 16 + l15] = f2bf(v);
            }
    }
    __syncthreads();

    // ---- write back: re-interleave rows d (r) and d+96 (i) into words
    {
        const int m = tid & 63;
        const int dr = tid >> 6;          // 0..3
        for (int pass = 0; pass < 24; pass++) {
            int d = dr + pass * 4;
            unsigned short rv = (unsigned short)actA[d * MPITCH + m];
            unsigned short iv = (unsigned short)actA[(d + BLK) * MPITCH + m];
            Xrow0[(size_t)d * MP + m] = (unsigned)rv | ((unsigned)iv << 16);
        }
    }
}

// ---------------------------------------------------------------------------
// K3: inverse rfft per (b,c): Xc -> yT [B*C, S] bf16
// ---------------------------------------------------------------------------
__global__ __launch_bounds__(256, 4) void fft_inv(const unsigned int* __restrict__ Xc,
                                                  __hip_bfloat16* __restrict__ yT,
                                                  const float2* __restrict__ tw4k,
                                                  const float2* __restrict__ tw8k) {
    __shared__ float2 zz[LDS_SZ];
    const int wg = blockIdx.x;
    const int tid = threadIdx.x;
    const unsigned int* Xrow = Xc + (size_t)wg * MP;

    const int a = tid & 31, cb3 = tid >> 5;
    #pragma unroll
    for (int it = 0; it < 16; it++) {
        int m = (a << 7) | (it << 3) | cb3;
        unsigned va = Xrow[m];
        int m2 = H_LEN - m;                       // partner (m=0 -> 4096)
        unsigned vb = Xrow[m2];
        float arv = bf2f((unsigned short)(va & 0xFFFF));
        float aiv = bf2f((unsigned short)(va >> 16));
        float brv = bf2f((unsigned short)(vb & 0xFFFF));
        float biv = bf2f((unsigned short)(vb >> 16));
        if (m == 0) { aiv = 0.f; biv = 0.f; }     // numpy irfft drops Im(Y0), Im(YH)
        float er = 0.5f * (arv + brv), ei = 0.5f * (aiv - biv);
        float dr = arv - brv, di = aiv + biv;
        float2 t = tw8k[m];                       // exp(-2*pi*i*m/8192); need exp(+..)
        float wcs = t.x, wsn = -t.y;
        float or_ = 0.5f * (wcs * dr - wsn * di);
        float oi = 0.5f * (wcs * di + wsn * dr);
        int c = crev12(m);
        zz[LDSPAD(c)] = make_float2(er - oi, ei + or_);
    }
    __syncthreads();

    fft_stages<true>(zz, tw4k, tid);

    __hip_bfloat162* orow = (__hip_bfloat162*)(yT + (size_t)wg * S_LEN);
    for (int k = tid; k < H_LEN; k += 256) {
        float2 z = zz[LDSPAD(k)];
        __hip_bfloat162 v;
        v.x = __float2bfloat16(C_INV * z.x);
        v.y = __float2bfloat16(C_INV * z.y);
        orow[k] = v;
    }
}

// ---------------------------------------------------------------------------
// K4: out[b,s,c] = x[b,s,c] + yT[b*C+c, s]
// ---------------------------------------------------------------------------
__global__ __launch_bounds__(256) void add_out(const __hip_bfloat16* __restrict__ yT,
                                               const float* __restrict__ x,
                                               float* __restrict__ out) {
    __shared__ float t[32][33];
    const int cb = blockIdx.x, sb = blockIdx.y, b = blockIdx.z;
    const int tx = threadIdx.x & 31, ty = threadIdx.x >> 5;
    const __hip_bfloat16* yp = yT + ((size_t)b * HIDDEN + cb * 32) * S_LEN + sb * 32;
    for (int i = 0; i < 4; i++)
        t[ty + 8 * i][tx] = __bfloat162float(yp[(size_t)(ty + 8 * i) * S_LEN + tx]);
    __syncthreads();
    const size_t off = ((size_t)b * S_LEN + sb * 32) * HIDDEN + cb * 32;
    const float* xp = x + off;
    float* op = out + off;
    for (int i = 0; i < 4; i++)
        op[(size_t)(ty + 8 * i) * HIDDEN + tx] =
            xp[(size_t)(ty + 8 * i) * HIDDEN + tx] + t[tx][ty + 8 * i];
}

// ---------------------------------------------------------------------------
extern "C" void kernel_launch(void* const* d_in, const int* in_sizes, int n_in,
                              void* d_out, int out_size, void* d_ws, size_t ws_size,
                              hipStream_t stream) {
    const float* x  = (const float*)d_in[0];
    const float* w1 = (const float*)d_in[1];
    const float* b1 = (const float*)d_in[2];
    const float* w2 = (const float*)d_in[3];
    const float* b2 = (const float*)d_in[4];
    float* out = (float*)d_out;

    // ws layout (all 16B-aligned):
    //   xT/yT  bf16 [B*C, S]              50.33 MB
    //   Xc     u32  [B*C, MP]             51.12 MB
    //   WT1/WT2 bf16 [NB,192,192]         2x0.59 MB
    //   bb1/bb2 f32 [NB,192]              2x6 KB
    //   tw4k/tw8k float2                  ~66 KB
    char* p = (char*)d_ws;
    __hip_bfloat16* xT = (__hip_bfloat16*)p;           p += (size_t)BATCH * HIDDEN * S_LEN * 2;
    unsigned int*   Xc = (unsigned int*)p;             p += (size_t)BATCH * HIDDEN * MP * 4;
    short* WT1 = (short*)p;                            p += (size_t)NB * KBIG * KBIG * 2;
    short* WT2 = (short*)p;                            p += (size_t)NB * KBIG * KBIG * 2;
    float* bb1 = (float*)p;                            p += (size_t)NB * KBIG * 4;
    float* bb2 = (float*)p;                            p += (size_t)NB * KBIG * 4;
    float2* tw4k = (float2*)p;                         p += (size_t)4096 * sizeof(float2);
    float2* tw8k = (float2*)p;                         p += (size_t)4100 * sizeof(float2);

    prep_weights<<<(NB * KBIG * KBIG + 255) / 256, 256, 0, stream>>>(
        w1, w2, b1, b2, WT1, WT2, bb1, bb2);

    init_twiddles<<<17, 256, 0, stream>>>(tw4k, tw8k);

    transpose_in<<<dim3(HIDDEN / 32, S_LEN / 32, BATCH), 256, 0, stream>>>(x, xT);

    fft_fwd<<<BATCH * HIDDEN, 256, 0, stream>>>(xT, Xc, tw4k, tw8k);

    mlp_mfma<<<dim3(65, NB, BATCH), 256, 0, stream>>>(WT1, WT2, bb1, bb2, Xc);

    fft_inv<<<BATCH * HIDDEN, 256, 0, stream>>>(Xc, xT /* as yT */, tw4k, tw8k);

    add_out<<<dim3(HIDDEN / 32, S_LEN / 32, BATCH), 256, 0, stream>>>(xT, x, out);
}

// Round 3
// 401.137 us; speedup vs baseline: 1.1238x; 1.1238x over previous
//
#include <hip/hip_runtime.h>
#include <hip/hip_bf16.h>

#define HIDDEN 768
#define NB 8
#define BLK 96
#define S_LEN 8192
#define H_LEN 4096
#define M_LEN 4097
#define MP 4160           // spectrum word pitch (65*64); one (r,i) bf16 word per mode
#define BATCH 4
#define KBIG 192          // 2*BLK (interleaved r/i channels)
#define TMOD 64           // modes per MLP workgroup
#define MPITCH 66         // act LDS row pitch in bf16 elems (33 words, odd -> conflict-free)

#define TWO_PI 6.28318530717958647692f
#define INV_SQRT_N 0.011048543456039806f   // 1/sqrt(8192)
#define C_INV 0.022097086912079612f        // 2/sqrt(8192)
#define LAM 0.01f

typedef __attribute__((ext_vector_type(8))) short short8;
typedef __attribute__((ext_vector_type(4))) float float4v;

__device__ __forceinline__ short f2bf(float f) {
    __hip_bfloat16 h = __float2bfloat16(f);
    return *reinterpret_cast<short*>(&h);
}
__device__ __forceinline__ float bf2f(unsigned short s) {
    __hip_bfloat16 h = *reinterpret_cast<__hip_bfloat16*>(&s);
    return __bfloat162float(h);
}
__device__ __forceinline__ float2 cmul(float2 a, float2 b) {
    return make_float2(a.x * b.x - a.y * b.y, a.x * b.y + a.y * b.x);
}

// ---------------------------------------------------------------------------
// P0: build bf16 big-weight matrices WT[n][out=192][kin=192] (kin interleaved
// r/i) for both layers, plus concatenated biases (fp32).
// ---------------------------------------------------------------------------
__global__ __launch_bounds__(256) void prep_weights(const float* __restrict__ w1,
                                                    const float* __restrict__ w2,
                                                    const float* __restrict__ b1,
                                                    const float* __restrict__ b2,
                                                    short* __restrict__ WT1,
                                                    short* __restrict__ WT2,
                                                    float* __restrict__ bb1,
                                                    float* __restrict__ bb2) {
    int idx = blockIdx.x * 256 + threadIdx.x;
    if (idx < NB * KBIG * KBIG) {
        int n = idx / (KBIG * KBIG);
        int r = idx % (KBIG * KBIG);
        int o = r / KBIG;
        int kin = r % KBIG;
        int d = kin >> 1;
        int im = kin & 1;
        {
            float w0 = w1[((size_t)(0 * NB + n) * BLK + d) * BLK + (o < BLK ? o : o - BLK)];
            float wi = w1[((size_t)(1 * NB + n) * BLK + d) * BLK + (o < BLK ? o : o - BLK)];
            float v = (o < BLK) ? (im ? -wi : w0) : (im ? w0 : wi);
            WT1[idx] = f2bf(v);
        }
        {
            float w0 = w2[((size_t)(0 * NB + n) * BLK + d) * BLK + (o < BLK ? o : o - BLK)];
            float wi = w2[((size_t)(1 * NB + n) * BLK + d) * BLK + (o < BLK ? o : o - BLK)];
            float v = (o < BLK) ? (im ? -wi : w0) : (im ? w0 : wi);
            WT2[idx] = f2bf(v);
        }
    }
    if (idx < NB * KBIG) {
        int n = idx / KBIG, o = idx % KBIG;
        bb1[idx] = (o < BLK) ? b1[(0 * NB + n) * BLK + o] : b1[(1 * NB + n) * BLK + o - BLK];
        bb2[idx] = (o < BLK) ? b2[(0 * NB + n) * BLK + o] : b2[(1 * NB + n) * BLK + o - BLK];
    }
}

// ---------------------------------------------------------------------------
// P1: twiddle tables.
//   tw4k[k] = exp(-2*pi*i*k/4096), k in [0,4096)
//   tw8k[m] = exp(-2*pi*i*m/8192), m in [0,4096]
// ---------------------------------------------------------------------------
__global__ __launch_bounds__(256) void init_twiddles(float2* __restrict__ tw4k,
                                                     float2* __restrict__ tw8k) {
    int i = blockIdx.x * 256 + threadIdx.x;
    if (i < 4096) {
        float ang = -TWO_PI * (float)i * (1.0f / 4096.0f);
        tw4k[i] = make_float2(cosf(ang), sinf(ang));
    }
    if (i <= 4096) {
        float ang = -TWO_PI * (float)i * (1.0f / 8192.0f);
        tw8k[i] = make_float2(cosf(ang), sinf(ang));
    }
}

// ---------------------------------------------------------------------------
// K0: x [B,S,C] f32  ->  xT [B*C, S] bf16   (32x32 LDS tiles, coalesced)
// ---------------------------------------------------------------------------
__global__ __launch_bounds__(256) void transpose_in(const float* __restrict__ x,
                                                    __hip_bfloat16* __restrict__ xT) {
    __shared__ float t[32][33];
    const int cb = blockIdx.x, sb = blockIdx.y, b = blockIdx.z;
    const int tx = threadIdx.x & 31, ty = threadIdx.x >> 5;
    const float* xp = x + ((size_t)b * S_LEN + sb * 32) * HIDDEN + cb * 32;
    for (int i = 0; i < 4; i++)
        t[ty + 8 * i][tx] = xp[(size_t)(ty + 8 * i) * HIDDEN + tx];
    __syncthreads();
    __hip_bfloat16* xq = xT + ((size_t)b * HIDDEN + cb * 32) * S_LEN + sb * 32;
    for (int i = 0; i < 4; i++)
        xq[(size_t)(ty + 8 * i) * S_LEN + tx] = __float2bfloat16(t[tx][ty + 8 * i]);
}

// ---------------------------------------------------------------------------
// In-place 16-point DFT (two radix-4 stages, compile-time W16 twiddles).
// Natural-order input v[n] -> natural-order output v[k]. INV => exp(+i...).
// ---------------------------------------------------------------------------
template<bool INV>
__device__ __forceinline__ void dft16(float2* v) {
    const float s3 = INV ? -1.f : 1.f;
    constexpr float C1 = 0.92387953251128674f;  // cos(pi/8)
    constexpr float S1 = 0.38268343236508977f;  // sin(pi/8)
    constexpr float R2 = 0.70710678118654752f;  // sqrt(2)/2
    float2 a[16];
    #pragma unroll
    for (int na = 0; na < 4; na++) {            // radix-4 over n_b (stride 4)
        float2 x0 = v[na], x1 = v[na + 4], x2 = v[na + 8], x3 = v[na + 12];
        float t0x = x0.x + x2.x, t0y = x0.y + x2.y;
        float t1x = x0.x - x2.x, t1y = x0.y - x2.y;
        float t2x = x1.x + x3.x, t2y = x1.y + x3.y;
        float t3x = x1.x - x3.x, t3y = x1.y - x3.y;
        a[na]      = make_float2(t0x + t2x, t0y + t2y);
        a[na + 8]  = make_float2(t0x - t2x, t0y - t2y);
        a[na + 4]  = make_float2(t1x + s3 * t3y, t1y - s3 * t3x);
        a[na + 12] = make_float2(t1x - s3 * t3y, t1y + s3 * t3x);
    }
    // a[na+4kb] *= W16^{na*kb};  W16^e = (cos(2pi e/16), -s3*sin(2pi e/16))
    auto tw = [s3](float2 z, float ce, float se) {
        return make_float2(z.x * ce + s3 * z.y * se, z.y * ce - s3 * z.x * se);
    };
    a[5]  = tw(a[5],  C1,  S1);   // e=1
    a[6]  = tw(a[6],  R2,  R2);   // e=2
    a[7]  = tw(a[7],  S1,  C1);   // e=3
    a[9]  = tw(a[9],  R2,  R2);   // e=2
    a[10] = tw(a[10], 0.f, 1.f);  // e=4
    a[11] = tw(a[11], -R2, R2);   // e=6
    a[13] = tw(a[13], S1,  C1);   // e=3
    a[14] = tw(a[14], -R2, R2);   // e=6
    a[15] = tw(a[15], -C1, -S1);  // e=9
    #pragma unroll
    for (int kb = 0; kb < 4; kb++) {            // radix-4 over n_a (contiguous)
        float2 x0 = a[4 * kb], x1 = a[4 * kb + 1], x2 = a[4 * kb + 2], x3 = a[4 * kb + 3];
        float t0x = x0.x + x2.x, t0y = x0.y + x2.y;
        float t1x = x0.x - x2.x, t1y = x0.y - x2.y;
        float t2x = x1.x + x3.x, t2y = x1.y + x3.y;
        float t3x = x1.x - x3.x, t3y = x1.y - x3.y;
        v[kb]      = make_float2(t0x + t2x, t0y + t2y);
        v[kb + 8]  = make_float2(t0x - t2x, t0y - t2y);
        v[kb + 4]  = make_float2(t1x + s3 * t3y, t1y - s3 * t3x);
        v[kb + 12] = make_float2(t1x - s3 * t3y, t1y + s3 * t3x);
    }
}

// ---------------------------------------------------------------------------
// 4096-point FFT as 16^3: three in-register DFT-16s, two LDS transposes.
// Thread t enters with v[j] = x[t + 256*j] (natural order), exits with
// v[k0] = X[t + 256*k0] (natural order).  arr must hold >= 256*17 float2.
// Ends after an LDS read with NO trailing barrier (callers barrier if they
// reuse arr).
// ---------------------------------------------------------------------------
template<bool INV>
__device__ __forceinline__ void fft3pass(float2* v, float2* arr,
                                         const float2* __restrict__ tw4k, int t) {
    const float sg = INV ? -1.f : 1.f;
    const int n0 = t & 15;
    const int hi = t >> 4;

    // stage 1: DFT16 over j (stride-256 samples), twiddle W4096^{t*p},
    // scatter to row n0+16p, col hi
    dft16<INV>(v);
    arr[n0 * 17 + hi] = v[0];
    #pragma unroll
    for (int p = 1; p < 16; p++) {
        float2 w = tw4k[(t * p) & 4095];
        arr[(n0 + 16 * p) * 17 + hi] = cmul(v[p], make_float2(w.x, sg * w.y));
    }
    __syncthreads();

    // stage 2: contiguous row read, DFT16 over n1=hi, twiddle W256^{n0*q},
    // scatter to row hi+16q, col n0
    #pragma unroll
    for (int n1 = 0; n1 < 16; n1++) v[n1] = arr[t * 17 + n1];
    __syncthreads();
    dft16<INV>(v);
    arr[hi * 17 + n0] = v[0];
    #pragma unroll
    for (int q = 1; q < 16; q++) {
        float2 w = tw4k[(16 * n0 * q) & 4095];
        arr[(hi + 16 * q) * 17 + n0] = cmul(v[q], make_float2(w.x, sg * w.y));
    }
    __syncthreads();

    // stage 3: contiguous row read, DFT16 over n0 -> X[t + 256*k0]
    #pragma unroll
    for (int i = 0; i < 16; i++) v[i] = arr[t * 17 + i];
    dft16<INV>(v);
}

// ---------------------------------------------------------------------------
// K1: forward rfft per (b,c) -> interleaved (r,i) bf16 words Xc[row][m]
// ---------------------------------------------------------------------------
__global__ __launch_bounds__(256, 4) void fft_fwd(const __hip_bfloat16* __restrict__ xT,
                                                  unsigned int* __restrict__ Xc,
                                                  const float2* __restrict__ tw4k,
                                                  const float2* __restrict__ tw8k) {
    __shared__ float2 arr[256 * 17];   // 34816 B; also reused flat [4096]
    const int wg = blockIdx.x;         // b*HIDDEN + c
    const int t = threadIdx.x;
    const __hip_bfloat162* xrow = (const __hip_bfloat162*)(xT + (size_t)wg * S_LEN);

    float2 v[16];
    #pragma unroll
    for (int j = 0; j < 16; j++) {     // coalesced: lane-consecutive 4B
        __hip_bfloat162 pz = xrow[t + 256 * j];
        v[j] = make_float2(__bfloat162float(pz.x), __bfloat162float(pz.y));
    }

    fft3pass<false>(v, arr, tw4k, t);

    // park natural-order spectrum in LDS for the rfft untangle
    __syncthreads();
    #pragma unroll
    for (int k0 = 0; k0 < 16; k0++) arr[t + 256 * k0] = v[k0];
    __syncthreads();

    unsigned int* Xrow = Xc + (size_t)wg * MP;
    for (int m = t; m <= H_LEN; m += 256) {
        int ia = m & (H_LEN - 1);
        int ib = (H_LEN - m) & (H_LEN - 1);
        float2 za = arr[ia];
        float2 zb = arr[ib];
        float er = 0.5f * (za.x + zb.x), ei = 0.5f * (za.y - zb.y);
        float dr = za.x - zb.x, di = za.y + zb.y;
        float or_ = 0.5f * di, oi = -0.5f * dr;
        float2 tt = tw8k[m];                       // exp(-2*pi*i*m/8192)
        float xrv = (er + tt.x * or_ - tt.y * oi) * INV_SQRT_N;
        float xiv = (ei + tt.x * oi + tt.y * or_) * INV_SQRT_N;
        unsigned wd = (unsigned short)f2bf(xrv) | ((unsigned)(unsigned short)f2bf(xiv) << 16);
        Xrow[m] = wd;
    }
}

// ---------------------------------------------------------------------------
// K2: MFMA block-diagonal complex MLP, in place over Xc.
// ---------------------------------------------------------------------------
__global__ __launch_bounds__(256) void mlp_mfma(const short* __restrict__ WT1,
                                                const short* __restrict__ WT2,
                                                const float* __restrict__ bb1,
                                                const float* __restrict__ bb2,
                                                unsigned int* __restrict__ Xc) {
    __shared__ short actA[KBIG * MPITCH];  // input, later final output
    __shared__ short actB[KBIG * MPITCH];  // layer-1 output
    const int tid = threadIdx.x;
    const int chunk = blockIdx.x;          // 0..64
    const int n = blockIdx.y;
    const int b = blockIdx.z;
    const int m0 = chunk * TMOD;
    unsigned int* __restrict__ Xrow0 =
        Xc + ((size_t)b * HIDDEN + (size_t)n * BLK) * MP + m0;

    // ---- stage: 96 channel rows x 64 modes, de-interleave to rows 2d / 2d+1
    {
        const int mw = tid & 31;           // word-pair: modes 2mw, 2mw+1
        const int dr = tid >> 5;           // 0..7
        int* a32 = (int*)actA;
        for (int pass = 0; pass < 12; pass++) {
            int d = dr + pass * 8;
            const uint2* src = (const uint2*)(Xrow0 + (size_t)d * MP);
            uint2 v = src[mw];
            unsigned rw = (v.x & 0xFFFFu) | (v.y << 16);
            unsigned iw = (v.x >> 16) | (v.y & 0xFFFF0000u);
            a32[(2 * d) * 33 + mw] = (int)rw;
            a32[(2 * d + 1) * 33 + mw] = (int)iw;
        }
    }
    __syncthreads();

    const int w = tid >> 6;
    const int l15 = tid & 15;
    const int q = (tid >> 4) & 3;
    const int outw = w * 48;

    // ---- layer 1 ----
    short8 wf[3][6];
    for (int nl = 0; nl < 3; nl++)
        for (int ks = 0; ks < 6; ks++)
            wf[nl][ks] = *(const short8*)(WT1 + ((size_t)n * KBIG + outw + nl * 16 + l15) * KBIG + ks * 32 + q * 8);

    for (int mt = 0; mt < 4; mt++) {
        float4v acc[3];
        for (int nl = 0; nl < 3; nl++)
            acc[nl] = *(const float4v*)(bb1 + n * KBIG + outw + nl * 16 + q * 4);
        for (int ks = 0; ks < 6; ks++) {
            short8 bf;
            const short* base = actA + (ks * 32 + q * 8) * MPITCH + mt * 16 + l15;
            #pragma unroll
            for (int j = 0; j < 8; j++) bf[j] = base[j * MPITCH];
            acc[0] = __builtin_amdgcn_mfma_f32_16x16x32_bf16(wf[0][ks], bf, acc[0], 0, 0, 0);
            acc[1] = __builtin_amdgcn_mfma_f32_16x16x32_bf16(wf[1][ks], bf, acc[1], 0, 0, 0);
            acc[2] = __builtin_amdgcn_mfma_f32_16x16x32_bf16(wf[2][ks], bf, acc[2], 0, 0, 0);
        }
        for (int nl = 0; nl < 3; nl++)
            #pragma unroll
            for (int reg = 0; reg < 4; reg++) {
                int out = outw + nl * 16 + q * 4 + reg;
                int row = (out < BLK) ? (out << 1) : (((out - BLK) << 1) | 1);
                actB[row * MPITCH + mt * 16 + l15] = f2bf(fmaxf(acc[nl][reg], 0.f));
            }
    }
    __syncthreads();

    // ---- layer 2 ----
    short8 wf2[3][6];
    for (int nl = 0; nl < 3; nl++)
        for (int ks = 0; ks < 6; ks++)
            wf2[nl][ks] = *(const short8*)(WT2 + ((size_t)n * KBIG + outw + nl * 16 + l15) * KBIG + ks * 32 + q * 8);

    for (int mt = 0; mt < 4; mt++) {
        float4v acc[3];
        for (int nl = 0; nl < 3; nl++)
            acc[nl] = *(const float4v*)(bb2 + n * KBIG + outw + nl * 16 + q * 4);
        for (int ks = 0; ks < 6; ks++) {
            short8 bf;
            const short* base = actB + (ks * 32 + q * 8) * MPITCH + mt * 16 + l15;
            #pragma unroll
            for (int j = 0; j < 8; j++) bf[j] = base[j * MPITCH];
            acc[0] = __builtin_amdgcn_mfma_f32_16x16x32_bf16(wf2[0][ks], bf, acc[0], 0, 0, 0);
            acc[1] = __builtin_amdgcn_mfma_f32_16x16x32_bf16(wf2[1][ks], bf, acc[1], 0, 0, 0);
            acc[2] = __builtin_amdgcn_mfma_f32_16x16x32_bf16(wf2[2][ks], bf, acc[2], 0, 0, 0);
        }
        for (int nl = 0; nl < 3; nl++)
            #pragma unroll
            for (int reg = 0; reg < 4; reg++) {
                int out = outw + nl * 16 + q * 4 + reg;
                float v = acc[nl][reg];
                v = copysignf(fmaxf(fabsf(v) - LAM, 0.f), v);
                actA[out * MPITCH + mt * 16 + l15] = f2bf(v);
            }
    }
    __syncthreads();

    // ---- write back: re-interleave rows d (r) and d+96 (i) into words
    {
        const int m = tid & 63;
        const int dr = tid >> 6;          // 0..3
        for (int pass = 0; pass < 24; pass++) {
            int d = dr + pass * 4;
            unsigned short rv = (unsigned short)actA[d * MPITCH + m];
            unsigned short iv = (unsigned short)actA[(d + BLK) * MPITCH + m];
            Xrow0[(size_t)d * MP + m] = (unsigned)rv | ((unsigned)iv << 16);
        }
    }
}

// ---------------------------------------------------------------------------
// K3: inverse rfft per (b,c): Xc -> yT [B*C, S] bf16
// Untangle fused into the (coalesced) register load; output straight from
// registers -> only 2 LDS round trips, 3 barriers.
// ---------------------------------------------------------------------------
__global__ __launch_bounds__(256, 4) void fft_inv(const unsigned int* __restrict__ Xc,
                                                  __hip_bfloat16* __restrict__ yT,
                                                  const float2* __restrict__ tw4k,
                                                  const float2* __restrict__ tw8k) {
    __shared__ float2 arr[256 * 17];
    const int wg = blockIdx.x;
    const int t = threadIdx.x;
    const unsigned int* Xrow = Xc + (size_t)wg * MP;

    float2 v[16];
    #pragma unroll
    for (int j = 0; j < 16; j++) {
        int m = t + 256 * j;                       // [0,4095], coalesced
        unsigned va = Xrow[m];
        unsigned vb = Xrow[H_LEN - m];             // descending, coalesced
        float arv = bf2f((unsigned short)(va & 0xFFFF));
        float aiv = bf2f((unsigned short)(va >> 16));
        float brv = bf2f((unsigned short)(vb & 0xFFFF));
        float biv = bf2f((unsigned short)(vb >> 16));
        if (m == 0) { aiv = 0.f; biv = 0.f; }      // numpy irfft drops Im(Y0), Im(YH)
        float er = 0.5f * (arv + brv), ei = 0.5f * (aiv - biv);
        float dr = arv - brv, di = aiv + biv;
        float2 tt = tw8k[m];                       // need exp(+2*pi*i*m/8192)
        float wcs = tt.x, wsn = -tt.y;
        float or_ = 0.5f * (wcs * dr - wsn * di);
        float oi = 0.5f * (wcs * di + wsn * dr);
        v[j] = make_float2(er - oi, ei + or_);
    }

    fft3pass<true>(v, arr, tw4k, t);

    __hip_bfloat162* orow = (__hip_bfloat162*)(yT + (size_t)wg * S_LEN);
    #pragma unroll
    for (int k0 = 0; k0 < 16; k0++) {              // coalesced 4B stores
        __hip_bfloat162 w;
        w.x = __float2bfloat16(C_INV * v[k0].x);
        w.y = __float2bfloat16(C_INV * v[k0].y);
        orow[t + 256 * k0] = w;
    }
}

// ---------------------------------------------------------------------------
// K4: out[b,s,c] = x[b,s,c] + yT[b*C+c, s]
// ---------------------------------------------------------------------------
__global__ __launch_bounds__(256) void add_out(const __hip_bfloat16* __restrict__ yT,
                                               const float* __restrict__ x,
                                               float* __restrict__ out) {
    __shared__ float t[32][33];
    const int cb = blockIdx.x, sb = blockIdx.y, b = blockIdx.z;
    const int tx = threadIdx.x & 31, ty = threadIdx.x >> 5;
    const __hip_bfloat16* yp = yT + ((size_t)b * HIDDEN + cb * 32) * S_LEN + sb * 32;
    for (int i = 0; i < 4; i++)
        t[ty + 8 * i][tx] = __bfloat162float(yp[(size_t)(ty + 8 * i) * S_LEN + tx]);
    __syncthreads();
    const size_t off = ((size_t)b * S_LEN + sb * 32) * HIDDEN + cb * 32;
    const float* xp = x + off;
    float* op = out + off;
    for (int i = 0; i < 4; i++)
        op[(size_t)(ty + 8 * i) * HIDDEN + tx] =
            xp[(size_t)(ty + 8 * i) * HIDDEN + tx] + t[tx][ty + 8 * i];
}

// ---------------------------------------------------------------------------
extern "C" void kernel_launch(void* const* d_in, const int* in_sizes, int n_in,
                              void* d_out, int out_size, void* d_ws, size_t ws_size,
                              hipStream_t stream) {
    const float* x  = (const float*)d_in[0];
    const float* w1 = (const float*)d_in[1];
    const float* b1 = (const float*)d_in[2];
    const float* w2 = (const float*)d_in[3];
    const float* b2 = (const float*)d_in[4];
    float* out = (float*)d_out;

    // ws layout (all 16B-aligned):
    //   xT/yT  bf16 [B*C, S]              50.33 MB
    //   Xc     u32  [B*C, MP]             51.12 MB
    //   WT1/WT2 bf16 [NB,192,192]         2x0.59 MB
    //   bb1/bb2 f32 [NB,192]              2x6 KB
    //   tw4k/tw8k float2                  ~66 KB
    char* p = (char*)d_ws;
    __hip_bfloat16* xT = (__hip_bfloat16*)p;           p += (size_t)BATCH * HIDDEN * S_LEN * 2;
    unsigned int*   Xc = (unsigned int*)p;             p += (size_t)BATCH * HIDDEN * MP * 4;
    short* WT1 = (short*)p;                            p += (size_t)NB * KBIG * KBIG * 2;
    short* WT2 = (short*)p;                            p += (size_t)NB * KBIG * KBIG * 2;
    float* bb1 = (float*)p;                            p += (size_t)NB * KBIG * 4;
    float* bb2 = (float*)p;                            p += (size_t)NB * KBIG * 4;
    float2* tw4k = (float2*)p;                         p += (size_t)4096 * sizeof(float2);
    float2* tw8k = (float2*)p;                         p += (size_t)4100 * sizeof(float2);

    prep_weights<<<(NB * KBIG * KBIG + 255) / 256, 256, 0, stream>>>(
        w1, w2, b1, b2, WT1, WT2, bb1, bb2);

    init_twiddles<<<17, 256, 0, stream>>>(tw4k, tw8k);

    transpose_in<<<dim3(HIDDEN / 32, S_LEN / 32, BATCH), 256, 0, stream>>>(x, xT);

    fft_fwd<<<BATCH * HIDDEN, 256, 0, stream>>>(xT, Xc, tw4k, tw8k);

    mlp_mfma<<<dim3(65, NB, BATCH), 256, 0, stream>>>(WT1, WT2, bb1, bb2, Xc);

    fft_inv<<<BATCH * HIDDEN, 256, 0, stream>>>(Xc, xT /* as yT */, tw4k, tw8k);

    add_out<<<dim3(HIDDEN / 32, S_LEN / 32, BATCH), 256, 0, stream>>>(xT, x, out);
}

// Round 4
// 396.004 us; speedup vs baseline: 1.1384x; 1.0130x over previous
//
#include <hip/hip_runtime.h>
#include <hip/hip_bf16.h>

#define HIDDEN 768
#define NB 8
#define BLK 96
#define S_LEN 8192
#define H_LEN 4096
#define M_LEN 4097
#define MP 4160           // spectrum word pitch (65*64); one (r,i) bf16 word per mode
#define BATCH 4
#define KBIG 192          // 2*BLK (interleaved r/i channels)
#define TMOD 64           // modes per MLP workgroup
#define APITCH 100        // act LDS row pitch in words (400 B -> 2-way, free)

#define TWO_PI 6.28318530717958647692f
#define INV_SQRT_N 0.011048543456039806f   // 1/sqrt(8192)
#define C_INV 0.022097086912079612f        // 2/sqrt(8192)
#define LAM 0.01f

typedef __attribute__((ext_vector_type(8))) short short8;
typedef __attribute__((ext_vector_type(4))) float float4v;

__device__ __forceinline__ short f2bf(float f) {
    __hip_bfloat16 h = __float2bfloat16(f);
    return *reinterpret_cast<short*>(&h);
}
__device__ __forceinline__ float bf2f(unsigned short s) {
    __hip_bfloat16 h = *reinterpret_cast<__hip_bfloat16*>(&s);
    return __bfloat162float(h);
}
__device__ __forceinline__ float2 cmul(float2 a, float2 b) {
    return make_float2(a.x * b.x - a.y * b.y, a.x * b.y + a.y * b.x);
}

// ---------------------------------------------------------------------------
// P0: build bf16 big-weight matrices WT[n][out=192][kin=192] (kin interleaved
// r/i) for both layers, plus concatenated biases (fp32).
// ---------------------------------------------------------------------------
__global__ __launch_bounds__(256) void prep_weights(const float* __restrict__ w1,
                                                    const float* __restrict__ w2,
                                                    const float* __restrict__ b1,
                                                    const float* __restrict__ b2,
                                                    short* __restrict__ WT1,
                                                    short* __restrict__ WT2,
                                                    float* __restrict__ bb1,
                                                    float* __restrict__ bb2) {
    int idx = blockIdx.x * 256 + threadIdx.x;
    if (idx < NB * KBIG * KBIG) {
        int n = idx / (KBIG * KBIG);
        int r = idx % (KBIG * KBIG);
        int o = r / KBIG;
        int kin = r % KBIG;
        int d = kin >> 1;
        int im = kin & 1;
        {
            float w0 = w1[((size_t)(0 * NB + n) * BLK + d) * BLK + (o < BLK ? o : o - BLK)];
            float wi = w1[((size_t)(1 * NB + n) * BLK + d) * BLK + (o < BLK ? o : o - BLK)];
            float v = (o < BLK) ? (im ? -wi : w0) : (im ? w0 : wi);
            WT1[idx] = f2bf(v);
        }
        {
            float w0 = w2[((size_t)(0 * NB + n) * BLK + d) * BLK + (o < BLK ? o : o - BLK)];
            float wi = w2[((size_t)(1 * NB + n) * BLK + d) * BLK + (o < BLK ? o : o - BLK)];
            float v = (o < BLK) ? (im ? -wi : w0) : (im ? w0 : wi);
            WT2[idx] = f2bf(v);
        }
    }
    if (idx < NB * KBIG) {
        int n = idx / KBIG, o = idx % KBIG;
        bb1[idx] = (o < BLK) ? b1[(0 * NB + n) * BLK + o] : b1[(1 * NB + n) * BLK + o - BLK];
        bb2[idx] = (o < BLK) ? b2[(0 * NB + n) * BLK + o] : b2[(1 * NB + n) * BLK + o - BLK];
    }
}

// ---------------------------------------------------------------------------
// P1: twiddle tables.
// ---------------------------------------------------------------------------
__global__ __launch_bounds__(256) void init_twiddles(float2* __restrict__ tw4k,
                                                     float2* __restrict__ tw8k) {
    int i = blockIdx.x * 256 + threadIdx.x;
    if (i < 4096) {
        float ang = -TWO_PI * (float)i * (1.0f / 4096.0f);
        tw4k[i] = make_float2(cosf(ang), sinf(ang));
    }
    if (i <= 4096) {
        float ang = -TWO_PI * (float)i * (1.0f / 8192.0f);
        tw8k[i] = make_float2(cosf(ang), sinf(ang));
    }
}

// ---------------------------------------------------------------------------
// K0: x [B,S,C] f32  ->  xT [B*C, S] bf16   (32x32 LDS tiles, coalesced)
// ---------------------------------------------------------------------------
__global__ __launch_bounds__(256) void transpose_in(const float* __restrict__ x,
                                                    __hip_bfloat16* __restrict__ xT) {
    __shared__ float t[32][33];
    const int cb = blockIdx.x, sb = blockIdx.y, b = blockIdx.z;
    const int tx = threadIdx.x & 31, ty = threadIdx.x >> 5;
    const float* xp = x + ((size_t)b * S_LEN + sb * 32) * HIDDEN + cb * 32;
    for (int i = 0; i < 4; i++)
        t[ty + 8 * i][tx] = xp[(size_t)(ty + 8 * i) * HIDDEN + tx];
    __syncthreads();
    __hip_bfloat16* xq = xT + ((size_t)b * HIDDEN + cb * 32) * S_LEN + sb * 32;
    for (int i = 0; i < 4; i++)
        xq[(size_t)(ty + 8 * i) * S_LEN + tx] = __float2bfloat16(t[tx][ty + 8 * i]);
}

// ---------------------------------------------------------------------------
// In-place 16-point DFT (two radix-4 stages, compile-time W16 twiddles).
// ---------------------------------------------------------------------------
template<bool INV>
__device__ __forceinline__ void dft16(float2* v) {
    const float s3 = INV ? -1.f : 1.f;
    constexpr float C1 = 0.92387953251128674f;  // cos(pi/8)
    constexpr float S1 = 0.38268343236508977f;  // sin(pi/8)
    constexpr float R2 = 0.70710678118654752f;  // sqrt(2)/2
    float2 a[16];
    #pragma unroll
    for (int na = 0; na < 4; na++) {            // radix-4 over n_b (stride 4)
        float2 x0 = v[na], x1 = v[na + 4], x2 = v[na + 8], x3 = v[na + 12];
        float t0x = x0.x + x2.x, t0y = x0.y + x2.y;
        float t1x = x0.x - x2.x, t1y = x0.y - x2.y;
        float t2x = x1.x + x3.x, t2y = x1.y + x3.y;
        float t3x = x1.x - x3.x, t3y = x1.y - x3.y;
        a[na]      = make_float2(t0x + t2x, t0y + t2y);
        a[na + 8]  = make_float2(t0x - t2x, t0y - t2y);
        a[na + 4]  = make_float2(t1x + s3 * t3y, t1y - s3 * t3x);
        a[na + 12] = make_float2(t1x - s3 * t3y, t1y + s3 * t3x);
    }
    auto tw = [s3](float2 z, float ce, float se) {
        return make_float2(z.x * ce + s3 * z.y * se, z.y * ce - s3 * z.x * se);
    };
    a[5]  = tw(a[5],  C1,  S1);   // e=1
    a[6]  = tw(a[6],  R2,  R2);   // e=2
    a[7]  = tw(a[7],  S1,  C1);   // e=3
    a[9]  = tw(a[9],  R2,  R2);   // e=2
    a[10] = tw(a[10], 0.f, 1.f);  // e=4
    a[11] = tw(a[11], -R2, R2);   // e=6
    a[13] = tw(a[13], S1,  C1);   // e=3
    a[14] = tw(a[14], -R2, R2);   // e=6
    a[15] = tw(a[15], -C1, -S1);  // e=9
    #pragma unroll
    for (int kb = 0; kb < 4; kb++) {            // radix-4 over n_a (contiguous)
        float2 x0 = a[4 * kb], x1 = a[4 * kb + 1], x2 = a[4 * kb + 2], x3 = a[4 * kb + 3];
        float t0x = x0.x + x2.x, t0y = x0.y + x2.y;
        float t1x = x0.x - x2.x, t1y = x0.y - x2.y;
        float t2x = x1.x + x3.x, t2y = x1.y + x3.y;
        float t3x = x1.x - x3.x, t3y = x1.y - x3.y;
        v[kb]      = make_float2(t0x + t2x, t0y + t2y);
        v[kb + 8]  = make_float2(t0x - t2x, t0y - t2y);
        v[kb + 4]  = make_float2(t1x + s3 * t3y, t1y - s3 * t3x);
        v[kb + 12] = make_float2(t1x - s3 * t3y, t1y + s3 * t3x);
    }
}

// ---------------------------------------------------------------------------
// 4096-point FFT as 16^3: three in-register DFT-16s, two LDS transposes.
// ---------------------------------------------------------------------------
template<bool INV>
__device__ __forceinline__ void fft3pass(float2* v, float2* arr,
                                         const float2* __restrict__ tw4k, int t) {
    const float sg = INV ? -1.f : 1.f;
    const int n0 = t & 15;
    const int hi = t >> 4;

    // stage 1: DFT16 over j, twiddle W4096^{t*p}, scatter (row n0+16p, col hi)
    dft16<INV>(v);
    arr[n0 * 17 + hi] = v[0];
    #pragma unroll
    for (int p = 1; p < 16; p++) {
        float2 w = tw4k[(t * p) & 4095];
        arr[(n0 + 16 * p) * 17 + hi] = cmul(v[p], make_float2(w.x, sg * w.y));
    }
    __syncthreads();

    // stage 2: row read, DFT16 over n1=hi, twiddle W256^{n0*q}, scatter
    #pragma unroll
    for (int n1 = 0; n1 < 16; n1++) v[n1] = arr[t * 17 + n1];
    __syncthreads();
    dft16<INV>(v);
    arr[hi * 17 + n0] = v[0];
    #pragma unroll
    for (int q = 1; q < 16; q++) {
        float2 w = tw4k[(16 * n0 * q) & 4095];
        arr[(hi + 16 * q) * 17 + n0] = cmul(v[q], make_float2(w.x, sg * w.y));
    }
    __syncthreads();

    // stage 3: row read, DFT16 over n0 -> X[t + 256*k0]
    #pragma unroll
    for (int i = 0; i < 16; i++) v[i] = arr[t * 17 + i];
    dft16<INV>(v);
}

// ---------------------------------------------------------------------------
// K1: forward rfft per (b,c) -> interleaved (r,i) bf16 words Xc[row][m]
// ---------------------------------------------------------------------------
__global__ __launch_bounds__(256, 4) void fft_fwd(const __hip_bfloat16* __restrict__ xT,
                                                  unsigned int* __restrict__ Xc,
                                                  const float2* __restrict__ tw4k,
                                                  const float2* __restrict__ tw8k) {
    __shared__ float2 arr[256 * 17];   // 34816 B; also reused flat [4096]
    const int wg = blockIdx.x;         // b*HIDDEN + c
    const int t = threadIdx.x;
    const __hip_bfloat162* xrow = (const __hip_bfloat162*)(xT + (size_t)wg * S_LEN);

    float2 v[16];
    #pragma unroll
    for (int j = 0; j < 16; j++) {     // coalesced: lane-consecutive 4B
        __hip_bfloat162 pz = xrow[t + 256 * j];
        v[j] = make_float2(__bfloat162float(pz.x), __bfloat162float(pz.y));
    }

    fft3pass<false>(v, arr, tw4k, t);

    // park natural-order spectrum in LDS for the rfft untangle
    __syncthreads();
    #pragma unroll
    for (int k0 = 0; k0 < 16; k0++) arr[t + 256 * k0] = v[k0];
    __syncthreads();

    unsigned int* Xrow = Xc + (size_t)wg * MP;
    for (int m = t; m <= H_LEN; m += 256) {
        int ia = m & (H_LEN - 1);
        int ib = (H_LEN - m) & (H_LEN - 1);
        float2 za = arr[ia];
        float2 zb = arr[ib];
        float er = 0.5f * (za.x + zb.x), ei = 0.5f * (za.y - zb.y);
        float dr = za.x - zb.x, di = za.y + zb.y;
        float or_ = 0.5f * di, oi = -0.5f * dr;
        float2 tt = tw8k[m];                       // exp(-2*pi*i*m/8192)
        float xrv = (er + tt.x * or_ - tt.y * oi) * INV_SQRT_N;
        float xiv = (ei + tt.x * oi + tt.y * or_) * INV_SQRT_N;
        unsigned wd = (unsigned short)f2bf(xrv) | ((unsigned)(unsigned short)f2bf(xiv) << 16);
        Xrow[m] = wd;
    }
}

// ---------------------------------------------------------------------------
// K2: MFMA block-diagonal complex MLP, in place over Xc.
// Transposed LDS layout act[mode][kword] (pitch APITCH words): the global u32
// word (r_d,i_d) IS the contiguous k-pair (2d,2d+1) -> staging is a raw copy,
// every B-fragment is one ds_read_b128, write-back is a coalesced uint2 copy.
// Waves 0-1 produce real outs (lo halves), waves 2-3 imag outs (hi halves).
// ---------------------------------------------------------------------------
__global__ __launch_bounds__(256) void mlp_mfma(const short* __restrict__ WT1,
                                                const short* __restrict__ WT2,
                                                const float* __restrict__ bb1,
                                                const float* __restrict__ bb2,
                                                unsigned int* __restrict__ Xc) {
    __shared__ unsigned int actA[TMOD * APITCH];  // 25.6 KB
    __shared__ unsigned int actB[TMOD * APITCH];  // 25.6 KB
    const int tid = threadIdx.x;
    const int chunk = blockIdx.x;          // 0..64
    const int n = blockIdx.y;
    const int b = blockIdx.z;
    const int m0 = chunk * TMOD;
    unsigned int* __restrict__ Xrow0 =
        Xc + ((size_t)b * HIDDEN + (size_t)n * BLK) * MP + m0;

    // ---- stage: word d of channel-row d -> act[mode][word d]; pure copy
    {
        const int mw = tid & 31;           // uint2 index: modes 2mw, 2mw+1
        const int dr = tid >> 5;           // 0..7
        for (int pass = 0; pass < 12; pass++) {
            int d = dr + pass * 8;
            uint2 v = ((const uint2*)(Xrow0 + (size_t)d * MP))[mw];
            actA[(2 * mw) * APITCH + d] = v.x;
            actA[(2 * mw + 1) * APITCH + d] = v.y;
        }
    }

    const int w = tid >> 6;
    const int l15 = tid & 15;
    const int q = (tid >> 4) & 3;
    const int outw = w * 48;

    // ---- weight fragments for BOTH layers up front (latency overlap) ----
    short8 wf[3][6], wf2[3][6];
    for (int nl = 0; nl < 3; nl++)
        for (int ks = 0; ks < 6; ks++) {
            wf[nl][ks]  = *(const short8*)(WT1 + ((size_t)n * KBIG + outw + nl * 16 + l15) * KBIG + ks * 32 + q * 8);
            wf2[nl][ks] = *(const short8*)(WT2 + ((size_t)n * KBIG + outw + nl * 16 + l15) * KBIG + ks * 32 + q * 8);
        }

    __syncthreads();

    // ---- layer 1 ----
    for (int mt = 0; mt < 4; mt++) {
        float4v acc[3];
        for (int nl = 0; nl < 3; nl++)
            acc[nl] = *(const float4v*)(bb1 + n * KBIG + outw + nl * 16 + q * 4);
        #pragma unroll
        for (int ks = 0; ks < 6; ks++) {
            short8 bf = *(const short8*)(&actA[(mt * 16 + l15) * APITCH + ks * 16 + q * 4]);
            acc[0] = __builtin_amdgcn_mfma_f32_16x16x32_bf16(wf[0][ks], bf, acc[0], 0, 0, 0);
            acc[1] = __builtin_amdgcn_mfma_f32_16x16x32_bf16(wf[1][ks], bf, acc[1], 0, 0, 0);
            acc[2] = __builtin_amdgcn_mfma_f32_16x16x32_bf16(wf[2][ks], bf, acc[2], 0, 0, 0);
        }
        short* sb = (short*)actB;
        for (int nl = 0; nl < 3; nl++)
            #pragma unroll
            for (int reg = 0; reg < 4; reg++) {
                int o = outw + nl * 16 + q * 4 + reg;
                int si = (o < BLK) ? (o << 1) : (((o - BLK) << 1) | 1);
                sb[(mt * 16 + l15) * (2 * APITCH) + si] = f2bf(fmaxf(acc[nl][reg], 0.f));
            }
    }
    __syncthreads();

    // ---- layer 2 ----
    for (int mt = 0; mt < 4; mt++) {
        float4v acc[3];
        for (int nl = 0; nl < 3; nl++)
            acc[nl] = *(const float4v*)(bb2 + n * KBIG + outw + nl * 16 + q * 4);
        #pragma unroll
        for (int ks = 0; ks < 6; ks++) {
            short8 bf = *(const short8*)(&actB[(mt * 16 + l15) * APITCH + ks * 16 + q * 4]);
            acc[0] = __builtin_amdgcn_mfma_f32_16x16x32_bf16(wf2[0][ks], bf, acc[0], 0, 0, 0);
            acc[1] = __builtin_amdgcn_mfma_f32_16x16x32_bf16(wf2[1][ks], bf, acc[1], 0, 0, 0);
            acc[2] = __builtin_amdgcn_mfma_f32_16x16x32_bf16(wf2[2][ks], bf, acc[2], 0, 0, 0);
        }
        short* sa = (short*)actA;
        for (int nl = 0; nl < 3; nl++)
            #pragma unroll
            for (int reg = 0; reg < 4; reg++) {
                int o = outw + nl * 16 + q * 4 + reg;
                float v = acc[nl][reg];
                v = copysignf(fmaxf(fabsf(v) - LAM, 0.f), v);
                int si = (o < BLK) ? (o << 1) : (((o - BLK) << 1) | 1);
                sa[(mt * 16 + l15) * (2 * APITCH) + si] = f2bf(v);
            }
    }
    __syncthreads();

    // ---- write back: act words are already in global format; uint2 copy
    {
        const int mw = tid & 31;
        const int dr = tid >> 5;
        for (int pass = 0; pass < 12; pass++) {
            int d = dr + pass * 8;
            uint2 v;
            v.x = actA[(2 * mw) * APITCH + d];
            v.y = actA[(2 * mw + 1) * APITCH + d];
            ((uint2*)(Xrow0 + (size_t)d * MP))[mw] = v;
        }
    }
}

// ---------------------------------------------------------------------------
// K3: inverse rfft per (b,c): Xc -> yT [B*C, S] bf16
// ---------------------------------------------------------------------------
__global__ __launch_bounds__(256, 4) void fft_inv(const unsigned int* __restrict__ Xc,
                                                  __hip_bfloat16* __restrict__ yT,
                                                  const float2* __restrict__ tw4k,
                                                  const float2* __restrict__ tw8k) {
    __shared__ float2 arr[256 * 17];
    const int wg = blockIdx.x;
    const int t = threadIdx.x;
    const unsigned int* Xrow = Xc + (size_t)wg * MP;

    float2 v[16];
    #pragma unroll
    for (int j = 0; j < 16; j++) {
        int m = t + 256 * j;                       // [0,4095], coalesced
        unsigned va = Xrow[m];
        unsigned vb = Xrow[H_LEN - m];             // descending, coalesced
        float arv = bf2f((unsigned short)(va & 0xFFFF));
        float aiv = bf2f((unsigned short)(va >> 16));
        float brv = bf2f((unsigned short)(vb & 0xFFFF));
        float biv = bf2f((unsigned short)(vb >> 16));
        if (m == 0) { aiv = 0.f; biv = 0.f; }      // numpy irfft drops Im(Y0), Im(YH)
        float er = 0.5f * (arv + brv), ei = 0.5f * (aiv - biv);
        float dr = arv - brv, di = aiv + biv;
        float2 tt = tw8k[m];                       // need exp(+2*pi*i*m/8192)
        float wcs = tt.x, wsn = -tt.y;
        float or_ = 0.5f * (wcs * dr - wsn * di);
        float oi = 0.5f * (wcs * di + wsn * dr);
        v[j] = make_float2(er - oi, ei + or_);
    }

    fft3pass<true>(v, arr, tw4k, t);

    __hip_bfloat162* orow = (__hip_bfloat162*)(yT + (size_t)wg * S_LEN);
    #pragma unroll
    for (int k0 = 0; k0 < 16; k0++) {              // coalesced 4B stores
        __hip_bfloat162 w;
        w.x = __float2bfloat16(C_INV * v[k0].x);
        w.y = __float2bfloat16(C_INV * v[k0].y);
        orow[t + 256 * k0] = w;
    }
}

// ---------------------------------------------------------------------------
// K4: out[b,s,c] = x[b,s,c] + yT[b*C+c, s]
// ---------------------------------------------------------------------------
__global__ __launch_bounds__(256) void add_out(const __hip_bfloat16* __restrict__ yT,
                                               const float* __restrict__ x,
                                               float* __restrict__ out) {
    __shared__ float t[32][33];
    const int cb = blockIdx.x, sb = blockIdx.y, b = blockIdx.z;
    const int tx = threadIdx.x & 31, ty = threadIdx.x >> 5;
    const __hip_bfloat16* yp = yT + ((size_t)b * HIDDEN + cb * 32) * S_LEN + sb * 32;
    for (int i = 0; i < 4; i++)
        t[ty + 8 * i][tx] = __bfloat162float(yp[(size_t)(ty + 8 * i) * S_LEN + tx]);
    __syncthreads();
    const size_t off = ((size_t)b * S_LEN + sb * 32) * HIDDEN + cb * 32;
    const float* xp = x + off;
    float* op = out + off;
    for (int i = 0; i < 4; i++)
        op[(size_t)(ty + 8 * i) * HIDDEN + tx] =
            xp[(size_t)(ty + 8 * i) * HIDDEN + tx] + t[tx][ty + 8 * i];
}

// ---------------------------------------------------------------------------
extern "C" void kernel_launch(void* const* d_in, const int* in_sizes, int n_in,
                              void* d_out, int out_size, void* d_ws, size_t ws_size,
                              hipStream_t stream) {
    const float* x  = (const float*)d_in[0];
    const float* w1 = (const float*)d_in[1];
    const float* b1 = (const float*)d_in[2];
    const float* w2 = (const float*)d_in[3];
    const float* b2 = (const float*)d_in[4];
    float* out = (float*)d_out;

    char* p = (char*)d_ws;
    __hip_bfloat16* xT = (__hip_bfloat16*)p;           p += (size_t)BATCH * HIDDEN * S_LEN * 2;
    unsigned int*   Xc = (unsigned int*)p;             p += (size_t)BATCH * HIDDEN * MP * 4;
    short* WT1 = (short*)p;                            p += (size_t)NB * KBIG * KBIG * 2;
    short* WT2 = (short*)p;                            p += (size_t)NB * KBIG * KBIG * 2;
    float* bb1 = (float*)p;                            p += (size_t)NB * KBIG * 4;
    float* bb2 = (float*)p;                            p += (size_t)NB * KBIG * 4;
    float2* tw4k = (float2*)p;                         p += (size_t)4096 * sizeof(float2);
    float2* tw8k = (float2*)p;                         p += (size_t)4100 * sizeof(float2);

    prep_weights<<<(NB * KBIG * KBIG + 255) / 256, 256, 0, stream>>>(
        w1, w2, b1, b2, WT1, WT2, bb1, bb2);

    init_twiddles<<<17, 256, 0, stream>>>(tw4k, tw8k);

    transpose_in<<<dim3(HIDDEN / 32, S_LEN / 32, BATCH), 256, 0, stream>>>(x, xT);

    fft_fwd<<<BATCH * HIDDEN, 256, 0, stream>>>(xT, Xc, tw4k, tw8k);

    mlp_mfma<<<dim3(65, NB, BATCH), 256, 0, stream>>>(WT1, WT2, bb1, bb2, Xc);

    fft_inv<<<BATCH * HIDDEN, 256, 0, stream>>>(Xc, xT /* as yT */, tw4k, tw8k);

    add_out<<<dim3(HIDDEN / 32, S_LEN / 32, BATCH), 256, 0, stream>>>(xT, x, out);
}

// Round 6
// 387.729 us; speedup vs baseline: 1.1627x; 1.0213x over previous
//
#include <hip/hip_runtime.h>
#include <hip/hip_bf16.h>

#define HIDDEN 768
#define NB 8
#define BLK 96
#define S_LEN 8192
#define H_LEN 4096
#define M_LEN 4097
#define MP 4160           // spectrum word pitch (65*64); one (r,i) bf16 word per mode
#define BATCH 4
#define KBIG 192          // 2*BLK (interleaved r/i channels)
#define TMOD 64           // modes per MLP workgroup
#define APITCH 100        // act LDS row pitch in words

#define TWO_PI 6.28318530717958647692f
#define INV_SQRT_N 0.011048543456039806f   // 1/sqrt(8192)
#define C_INV 0.022097086912079612f        // 2/sqrt(8192)
#define LAM 0.01f

typedef __attribute__((ext_vector_type(8))) short short8;
typedef __attribute__((ext_vector_type(4))) float float4v;

__device__ __forceinline__ short f2bf(float f) {
    __hip_bfloat16 h = __float2bfloat16(f);
    return *reinterpret_cast<short*>(&h);
}
__device__ __forceinline__ float bf2f(unsigned short s) {
    __hip_bfloat16 h = *reinterpret_cast<__hip_bfloat16*>(&s);
    return __bfloat162float(h);
}
__device__ __forceinline__ unsigned pack2bf(float a, float b) {
    return (unsigned)(unsigned short)f2bf(a) | ((unsigned)(unsigned short)f2bf(b) << 16);
}
__device__ __forceinline__ float2 cmul(float2 a, float2 b) {
    return make_float2(a.x * b.x - a.y * b.y, a.x * b.y + a.y * b.x);
}

// ---------------------------------------------------------------------------
// P0: big-weight matrices WT[n][o'=192][kin=192], OUTPUT rows interleaved:
//   o' = 2*oc   -> real-part row of channel oc
//   o' = 2*oc+1 -> imag-part row of channel oc
// kin unchanged (even = r_d, odd = i_d). Biases bb interleaved the same way.
// With this, a wave's 4 consecutive acc outputs form word-pairs that match
// the global (r,i) u32 word format directly.
// ---------------------------------------------------------------------------
__global__ __launch_bounds__(256) void prep_weights(const float* __restrict__ w1,
                                                    const float* __restrict__ w2,
                                                    const float* __restrict__ b1,
                                                    const float* __restrict__ b2,
                                                    short* __restrict__ WT1,
                                                    short* __restrict__ WT2,
                                                    float* __restrict__ bb1,
                                                    float* __restrict__ bb2) {
    int idx = blockIdx.x * 256 + threadIdx.x;
    if (idx < NB * KBIG * KBIG) {
        int n = idx / (KBIG * KBIG);
        int r = idx % (KBIG * KBIG);
        int op = r / KBIG;         // interleaved output row
        int kin = r % KBIG;
        int oc = op >> 1;
        int oim = op & 1;
        int d = kin >> 1;
        int im = kin & 1;
        {
            float w0 = w1[((size_t)(0 * NB + n) * BLK + d) * BLK + oc];
            float wi = w1[((size_t)(1 * NB + n) * BLK + d) * BLK + oc];
            float v = oim ? (im ? w0 : wi) : (im ? -wi : w0);
            WT1[idx] = f2bf(v);
        }
        {
            float w0 = w2[((size_t)(0 * NB + n) * BLK + d) * BLK + oc];
            float wi = w2[((size_t)(1 * NB + n) * BLK + d) * BLK + oc];
            float v = oim ? (im ? w0 : wi) : (im ? -wi : w0);
            WT2[idx] = f2bf(v);
        }
    }
    if (idx < NB * KBIG) {
        int n = idx / KBIG, op = idx % KBIG;
        int oc = op >> 1, oim = op & 1;
        bb1[idx] = oim ? b1[(1 * NB + n) * BLK + oc] : b1[(0 * NB + n) * BLK + oc];
        bb2[idx] = oim ? b2[(1 * NB + n) * BLK + oc] : b2[(0 * NB + n) * BLK + oc];
    }
}

// ---------------------------------------------------------------------------
// P1: twiddle tables.
// ---------------------------------------------------------------------------
__global__ __launch_bounds__(256) void init_twiddles(float2* __restrict__ tw4k,
                                                     float2* __restrict__ tw8k) {
    int i = blockIdx.x * 256 + threadIdx.x;
    if (i < 4096) {
        float ang = -TWO_PI * (float)i * (1.0f / 4096.0f);
        tw4k[i] = make_float2(cosf(ang), sinf(ang));
    }
    if (i <= 4096) {
        float ang = -TWO_PI * (float)i * (1.0f / 8192.0f);
        tw8k[i] = make_float2(cosf(ang), sinf(ang));
    }
}

// ---------------------------------------------------------------------------
// K0: x [B,S,C] f32  ->  xT [B*C, S] bf16   (32x32 LDS tiles, coalesced)
// ---------------------------------------------------------------------------
__global__ __launch_bounds__(256) void transpose_in(const float* __restrict__ x,
                                                    __hip_bfloat16* __restrict__ xT) {
    __shared__ float t[32][33];
    const int cb = blockIdx.x, sb = blockIdx.y, b = blockIdx.z;
    const int tx = threadIdx.x & 31, ty = threadIdx.x >> 5;
    const float* xp = x + ((size_t)b * S_LEN + sb * 32) * HIDDEN + cb * 32;
    for (int i = 0; i < 4; i++)
        t[ty + 8 * i][tx] = xp[(size_t)(ty + 8 * i) * HIDDEN + tx];
    __syncthreads();
    __hip_bfloat16* xq = xT + ((size_t)b * HIDDEN + cb * 32) * S_LEN + sb * 32;
    for (int i = 0; i < 4; i++)
        xq[(size_t)(ty + 8 * i) * S_LEN + tx] = __float2bfloat16(t[tx][ty + 8 * i]);
}

// ---------------------------------------------------------------------------
// In-place 16-point DFT (two radix-4 stages, compile-time W16 twiddles).
// ---------------------------------------------------------------------------
template<bool INV>
__device__ __forceinline__ void dft16(float2* v) {
    const float s3 = INV ? -1.f : 1.f;
    constexpr float C1 = 0.92387953251128674f;  // cos(pi/8)
    constexpr float S1 = 0.38268343236508977f;  // sin(pi/8)
    constexpr float R2 = 0.70710678118654752f;  // sqrt(2)/2
    float2 a[16];
    #pragma unroll
    for (int na = 0; na < 4; na++) {            // radix-4 over n_b (stride 4)
        float2 x0 = v[na], x1 = v[na + 4], x2 = v[na + 8], x3 = v[na + 12];
        float t0x = x0.x + x2.x, t0y = x0.y + x2.y;
        float t1x = x0.x - x2.x, t1y = x0.y - x2.y;
        float t2x = x1.x + x3.x, t2y = x1.y + x3.y;
        float t3x = x1.x - x3.x, t3y = x1.y - x3.y;
        a[na]      = make_float2(t0x + t2x, t0y + t2y);
        a[na + 8]  = make_float2(t0x - t2x, t0y - t2y);
        a[na + 4]  = make_float2(t1x + s3 * t3y, t1y - s3 * t3x);
        a[na + 12] = make_float2(t1x - s3 * t3y, t1y + s3 * t3x);
    }
    auto tw = [s3](float2 z, float ce, float se) {
        return make_float2(z.x * ce + s3 * z.y * se, z.y * ce - s3 * z.x * se);
    };
    a[5]  = tw(a[5],  C1,  S1);   // e=1
    a[6]  = tw(a[6],  R2,  R2);   // e=2
    a[7]  = tw(a[7],  S1,  C1);   // e=3
    a[9]  = tw(a[9],  R2,  R2);   // e=2
    a[10] = tw(a[10], 0.f, 1.f);  // e=4
    a[11] = tw(a[11], -R2, R2);   // e=6
    a[13] = tw(a[13], S1,  C1);   // e=3
    a[14] = tw(a[14], -R2, R2);   // e=6
    a[15] = tw(a[15], -C1, -S1);  // e=9
    #pragma unroll
    for (int kb = 0; kb < 4; kb++) {            // radix-4 over n_a (contiguous)
        float2 x0 = a[4 * kb], x1 = a[4 * kb + 1], x2 = a[4 * kb + 2], x3 = a[4 * kb + 3];
        float t0x = x0.x + x2.x, t0y = x0.y + x2.y;
        float t1x = x0.x - x2.x, t1y = x0.y - x2.y;
        float t2x = x1.x + x3.x, t2y = x1.y + x3.y;
        float t3x = x1.x - x3.x, t3y = x1.y - x3.y;
        v[kb]      = make_float2(t0x + t2x, t0y + t2y);
        v[kb + 8]  = make_float2(t0x - t2x, t0y - t2y);
        v[kb + 4]  = make_float2(t1x + s3 * t3y, t1y - s3 * t3x);
        v[kb + 12] = make_float2(t1x - s3 * t3y, t1y + s3 * t3x);
    }
}

// ---------------------------------------------------------------------------
// 4096-point FFT as 16^3: three in-register DFT-16s, two LDS transposes.
// ---------------------------------------------------------------------------
template<bool INV>
__device__ __forceinline__ void fft3pass(float2* v, float2* arr,
                                         const float2* __restrict__ tw4k, int t) {
    const float sg = INV ? -1.f : 1.f;
    const int n0 = t & 15;
    const int hi = t >> 4;

    // stage 1: DFT16 over j, twiddle W4096^{t*p}, scatter (row n0+16p, col hi)
    dft16<INV>(v);
    arr[n0 * 17 + hi] = v[0];
    #pragma unroll
    for (int p = 1; p < 16; p++) {
        float2 w = tw4k[(t * p) & 4095];
        arr[(n0 + 16 * p) * 17 + hi] = cmul(v[p], make_float2(w.x, sg * w.y));
    }
    __syncthreads();

    // stage 2: row read, DFT16 over n1=hi, twiddle W256^{n0*q}, scatter
    #pragma unroll
    for (int n1 = 0; n1 < 16; n1++) v[n1] = arr[t * 17 + n1];
    __syncthreads();
    dft16<INV>(v);
    arr[hi * 17 + n0] = v[0];
    #pragma unroll
    for (int q = 1; q < 16; q++) {
        float2 w = tw4k[(16 * n0 * q) & 4095];
        arr[(hi + 16 * q) * 17 + n0] = cmul(v[q], make_float2(w.x, sg * w.y));
    }
    __syncthreads();

    // stage 3: row read, DFT16 over n0 -> X[t + 256*k0]
    #pragma unroll
    for (int i = 0; i < 16; i++) v[i] = arr[t * 17 + i];
    dft16<INV>(v);
}

// ---------------------------------------------------------------------------
// K1: forward rfft per (b,c) -> interleaved (r,i) bf16 words Xc[row][m]
// ---------------------------------------------------------------------------
__global__ __launch_bounds__(256, 4) void fft_fwd(const __hip_bfloat16* __restrict__ xT,
                                                  unsigned int* __restrict__ Xc,
                                                  const float2* __restrict__ tw4k,
                                                  const float2* __restrict__ tw8k) {
    __shared__ __align__(16) float2 arr[256 * 17];   // 34816 B; reused flat [4096]
    const int wg = blockIdx.x;         // b*HIDDEN + c
    const int t = threadIdx.x;
    const __hip_bfloat162* xrow = (const __hip_bfloat162*)(xT + (size_t)wg * S_LEN);

    float2 v[16];
    #pragma unroll
    for (int j = 0; j < 16; j++) {     // coalesced: lane-consecutive 4B
        __hip_bfloat162 pz = xrow[t + 256 * j];
        v[j] = make_float2(__bfloat162float(pz.x), __bfloat162float(pz.y));
    }

    fft3pass<false>(v, arr, tw4k, t);

    // park natural-order spectrum in LDS for the rfft untangle
    __syncthreads();
    #pragma unroll
    for (int k0 = 0; k0 < 16; k0++) arr[t + 256 * k0] = v[k0];
    __syncthreads();

    unsigned int* Xrow = Xc + (size_t)wg * MP;
    for (int m = t; m <= H_LEN; m += 256) {
        int ia = m & (H_LEN - 1);
        int ib = (H_LEN - m) & (H_LEN - 1);
        float2 za = arr[ia];
        float2 zb = arr[ib];
        float er = 0.5f * (za.x + zb.x), ei = 0.5f * (za.y - zb.y);
        float dr = za.x - zb.x, di = za.y + zb.y;
        float or_ = 0.5f * di, oi = -0.5f * dr;
        float2 tt = tw8k[m];                       // exp(-2*pi*i*m/8192)
        float xrv = (er + tt.x * or_ - tt.y * oi) * INV_SQRT_N;
        float xiv = (ei + tt.x * oi + tt.y * or_) * INV_SQRT_N;
        unsigned wd = (unsigned short)f2bf(xrv) | ((unsigned)(unsigned short)f2bf(xiv) << 16);
        Xrow[m] = wd;
    }
}

// ---------------------------------------------------------------------------
// K2: MFMA block-diagonal complex MLP, in place over Xc.
// act LDS layout: [mode m][kword d] (pitch APITCH words); word d = (k=2d, k=2d+1).
// Staging/writeback: lane owns (m = tid&63, 4-word d-group) -> 4 coalesced
// global dwords + one ds b128 op (structural-min banking, slot = m mod 8).
// B-fragments: one ds_read_b128 each. Epilogues: interleaved-output weights
// make acc regs word-pairs -> one ds_write_b64 per nl (4-way = b64 min).
// ---------------------------------------------------------------------------
__global__ __launch_bounds__(256, 3) void mlp_mfma(const short* __restrict__ WT1,
                                                   const short* __restrict__ WT2,
                                                   const float* __restrict__ bb1,
                                                   const float* __restrict__ bb2,
                                                   unsigned int* __restrict__ Xc) {
    __shared__ __align__(16) unsigned int actA[TMOD * APITCH];  // 25.6 KB
    __shared__ __align__(16) unsigned int actB[TMOD * APITCH];  // 25.6 KB
    const int tid = threadIdx.x;
    const int chunk = blockIdx.x;          // 0..64
    const int n = blockIdx.y;
    const int b = blockIdx.z;
    const int m0 = chunk * TMOD;
    unsigned int* __restrict__ Xrow0 =
        Xc + ((size_t)b * HIDDEN + (size_t)n * BLK) * MP + m0;

    const int w = tid >> 6;                // wave 0..3
    const int l15 = tid & 15;
    const int q = (tid >> 4) & 3;
    const int outw = w * 48;
    const int mstg = tid & 63;             // staging: mode owned by this lane

    // ---- stage: 6 passes of 4 coalesced global dwords -> 1 b128 LDS write
    #pragma unroll
    for (int dp = 0; dp < 6; dp++) {
        int d0 = dp * 16 + w * 4;
        uint4 vv;
        vv.x = Xrow0[(size_t)(d0 + 0) * MP + mstg];
        vv.y = Xrow0[(size_t)(d0 + 1) * MP + mstg];
        vv.z = Xrow0[(size_t)(d0 + 2) * MP + mstg];
        vv.w = Xrow0[(size_t)(d0 + 3) * MP + mstg];
        *(uint4*)&actA[mstg * APITCH + d0] = vv;
    }

    // ---- layer-1 weight fragments (latency overlaps staging + barrier)
    short8 wf[3][6];
    for (int nl = 0; nl < 3; nl++)
        for (int ks = 0; ks < 6; ks++)
            wf[nl][ks] = *(const short8*)(WT1 + ((size_t)n * KBIG + outw + nl * 16 + l15) * KBIG + ks * 32 + q * 8);

    __syncthreads();

    // ---- layer 1 ----
    for (int mt = 0; mt < 4; mt++) {
        float4v acc[3];
        for (int nl = 0; nl < 3; nl++)
            acc[nl] = *(const float4v*)(bb1 + n * KBIG + outw + nl * 16 + q * 4);
        #pragma unroll
        for (int ks = 0; ks < 6; ks++) {
            short8 bf = *(const short8*)(&actA[(mt * 16 + l15) * APITCH + ks * 16 + q * 4]);
            acc[0] = __builtin_amdgcn_mfma_f32_16x16x32_bf16(wf[0][ks], bf, acc[0], 0, 0, 0);
            acc[1] = __builtin_amdgcn_mfma_f32_16x16x32_bf16(wf[1][ks], bf, acc[1], 0, 0, 0);
            acc[2] = __builtin_amdgcn_mfma_f32_16x16x32_bf16(wf[2][ks], bf, acc[2], 0, 0, 0);
        }
        #pragma unroll
        for (int nl = 0; nl < 3; nl++) {
            uint2 st;
            st.x = pack2bf(fmaxf(acc[nl][0], 0.f), fmaxf(acc[nl][1], 0.f));
            st.y = pack2bf(fmaxf(acc[nl][2], 0.f), fmaxf(acc[nl][3], 0.f));
            *(uint2*)&actB[(mt * 16 + l15) * APITCH + outw / 2 + nl * 8 + q * 2] = st;
        }
    }

    // ---- layer-2 weight fragments (latency overlaps barrier)
    short8 wf2[3][6];
    for (int nl = 0; nl < 3; nl++)
        for (int ks = 0; ks < 6; ks++)
            wf2[nl][ks] = *(const short8*)(WT2 + ((size_t)n * KBIG + outw + nl * 16 + l15) * KBIG + ks * 32 + q * 8);

    __syncthreads();

    // ---- layer 2 ----
    for (int mt = 0; mt < 4; mt++) {
        float4v acc[3];
        for (int nl = 0; nl < 3; nl++)
            acc[nl] = *(const float4v*)(bb2 + n * KBIG + outw + nl * 16 + q * 4);
        #pragma unroll
        for (int ks = 0; ks < 6; ks++) {
            short8 bf = *(const short8*)(&actB[(mt * 16 + l15) * APITCH + ks * 16 + q * 4]);
            acc[0] = __builtin_amdgcn_mfma_f32_16x16x32_bf16(wf2[0][ks], bf, acc[0], 0, 0, 0);
            acc[1] = __builtin_amdgcn_mfma_f32_16x16x32_bf16(wf2[1][ks], bf, acc[1], 0, 0, 0);
            acc[2] = __builtin_amdgcn_mfma_f32_16x16x32_bf16(wf2[2][ks], bf, acc[2], 0, 0, 0);
        }
        #pragma unroll
        for (int nl = 0; nl < 3; nl++) {
            float v0 = acc[nl][0], v1 = acc[nl][1], v2 = acc[nl][2], v3 = acc[nl][3];
            v0 = copysignf(fmaxf(fabsf(v0) - LAM, 0.f), v0);
            v1 = copysignf(fmaxf(fabsf(v1) - LAM, 0.f), v1);
            v2 = copysignf(fmaxf(fabsf(v2) - LAM, 0.f), v2);
            v3 = copysignf(fmaxf(fabsf(v3) - LAM, 0.f), v3);
            uint2 st;
            st.x = pack2bf(v0, v1);
            st.y = pack2bf(v2, v3);
            *(uint2*)&actA[(mt * 16 + l15) * APITCH + outw / 2 + nl * 8 + q * 2] = st;
        }
    }
    __syncthreads();

    // ---- write back: words already in global (r,i) format; b128 + coalesced
    #pragma unroll
    for (int dp = 0; dp < 6; dp++) {
        int d0 = dp * 16 + w * 4;
        uint4 vv = *(const uint4*)&actA[mstg * APITCH + d0];
        Xrow0[(size_t)(d0 + 0) * MP + mstg] = vv.x;
        Xrow0[(size_t)(d0 + 1) * MP + mstg] = vv.y;
        Xrow0[(size_t)(d0 + 2) * MP + mstg] = vv.z;
        Xrow0[(size_t)(d0 + 3) * MP + mstg] = vv.w;
    }
}

// ---------------------------------------------------------------------------
// K3: inverse rfft per (b,c): Xc -> yT [B*C, S] bf16
// ---------------------------------------------------------------------------
__global__ __launch_bounds__(256, 4) void fft_inv(const unsigned int* __restrict__ Xc,
                                                  __hip_bfloat16* __restrict__ yT,
                                                  const float2* __restrict__ tw4k,
                                                  const float2* __restrict__ tw8k) {
    __shared__ __align__(16) float2 arr[256 * 17];
    const int wg = blockIdx.x;
    const int t = threadIdx.x;
    const unsigned int* Xrow = Xc + (size_t)wg * MP;

    float2 v[16];
    #pragma unroll
    for (int j = 0; j < 16; j++) {
        int m = t + 256 * j;                       // [0,4095], coalesced
        unsigned va = Xrow[m];
        unsigned vb = Xrow[H_LEN - m];             // descending, coalesced
        float arv = bf2f((unsigned short)(va & 0xFFFF));
        float aiv = bf2f((unsigned short)(va >> 16));
        float brv = bf2f((unsigned short)(vb & 0xFFFF));
        float biv = bf2f((unsigned short)(vb >> 16));
        if (m == 0) { aiv = 0.f; biv = 0.f; }      // numpy irfft drops Im(Y0), Im(YH)
        float er = 0.5f * (arv + brv), ei = 0.5f * (aiv - biv);
        float dr = arv - brv, di = aiv + biv;
        float2 tt = tw8k[m];                       // need exp(+2*pi*i*m/8192)
        float wcs = tt.x, wsn = -tt.y;
        float or_ = 0.5f * (wcs * dr - wsn * di);
        float oi = 0.5f * (wcs * di + wsn * dr);
        v[j] = make_float2(er - oi, ei + or_);
    }

    fft3pass<true>(v, arr, tw4k, t);

    __hip_bfloat162* orow = (__hip_bfloat162*)(yT + (size_t)wg * S_LEN);
    #pragma unroll
    for (int k0 = 0; k0 < 16; k0++) {              // coalesced 4B stores
        __hip_bfloat162 w;
        w.x = __float2bfloat16(C_INV * v[k0].x);
        w.y = __float2bfloat16(C_INV * v[k0].y);
        orow[t + 256 * k0] = w;
    }
}

// ---------------------------------------------------------------------------
// K4: out[b,s,c] = x[b,s,c] + yT[b*C+c, s]
// ---------------------------------------------------------------------------
__global__ __launch_bounds__(256) void add_out(const __hip_bfloat16* __restrict__ yT,
                                               const float* __restrict__ x,
                                               float* __restrict__ out) {
    __shared__ float t[32][33];
    const int cb = blockIdx.x, sb = blockIdx.y, b = blockIdx.z;
    const int tx = threadIdx.x & 31, ty = threadIdx.x >> 5;
    const __hip_bfloat16* yp = yT + ((size_t)b * HIDDEN + cb * 32) * S_LEN + sb * 32;
    for (int i = 0; i < 4; i++)
        t[ty + 8 * i][tx] = __bfloat162float(yp[(size_t)(ty + 8 * i) * S_LEN + tx]);
    __syncthreads();
    const size_t off = ((size_t)b * S_LEN + sb * 32) * HIDDEN + cb * 32;
    const float* xp = x + off;
    float* op = out + off;
    for (int i = 0; i < 4; i++)
        op[(size_t)(ty + 8 * i) * HIDDEN + tx] =
            xp[(size_t)(ty + 8 * i) * HIDDEN + tx] + t[tx][ty + 8 * i];
}

// ---------------------------------------------------------------------------
extern "C" void kernel_launch(void* const* d_in, const int* in_sizes, int n_in,
                              void* d_out, int out_size, void* d_ws, size_t ws_size,
                              hipStream_t stream) {
    const float* x  = (const float*)d_in[0];
    const float* w1 = (const float*)d_in[1];
    const float* b1 = (const float*)d_in[2];
    const float* w2 = (const float*)d_in[3];
    const float* b2 = (const float*)d_in[4];
    float* out = (float*)d_out;

    char* p = (char*)d_ws;
    __hip_bfloat16* xT = (__hip_bfloat16*)p;           p += (size_t)BATCH * HIDDEN * S_LEN * 2;
    unsigned int*   Xc = (unsigned int*)p;             p += (size_t)BATCH * HIDDEN * MP * 4;
    short* WT1 = (short*)p;                            p += (size_t)NB * KBIG * KBIG * 2;
    short* WT2 = (short*)p;                            p += (size_t)NB * KBIG * KBIG * 2;
    float* bb1 = (float*)p;                            p += (size_t)NB * KBIG * 4;
    float* bb2 = (float*)p;                            p += (size_t)NB * KBIG * 4;
    float2* tw4k = (float2*)p;                         p += (size_t)4096 * sizeof(float2);
    float2* tw8k = (float2*)p;                         p += (size_t)4100 * sizeof(float2);

    prep_weights<<<(NB * KBIG * KBIG + 255) / 256, 256, 0, stream>>>(
        w1, w2, b1, b2, WT1, WT2, bb1, bb2);

    init_twiddles<<<17, 256, 0, stream>>>(tw4k, tw8k);

    transpose_in<<<dim3(HIDDEN / 32, S_LEN / 32, BATCH), 256, 0, stream>>>(x, xT);

    fft_fwd<<<BATCH * HIDDEN, 256, 0, stream>>>(xT, Xc, tw4k, tw8k);

    mlp_mfma<<<dim3(65, NB, BATCH), 256, 0, stream>>>(WT1, WT2, bb1, bb2, Xc);

    fft_inv<<<BATCH * HIDDEN, 256, 0, stream>>>(Xc, xT /* as yT */, tw4k, tw8k);

    add_out<<<dim3(HIDDEN / 32, S_LEN / 32, BATCH), 256, 0, stream>>>(xT, x, out);
}